// Round 1
// baseline (441.657 us; speedup 1.0000x reference)
//
#include <hip/hip_runtime.h>
#include <math.h>

#define NB 4
#define NS 2048
#define NF 256
#define NH 8
#define ND 32

constexpr float LN_EPS = 1e-3f;
constexpr float QSCALE = 0.35355339059327373f; // 1/sqrt(H) = 1/sqrt(8)

// ---------------------------------------------------------------------------
// Kernel 1: QKV projection.  C[M=8192, N=256] = x[M,256] @ W[256,256]
// Output scattered to [B,H,S,D] layout; Q additionally scaled by 1/sqrt(H).
// Tile: 64x64, BK=16, 256 threads, 4x4 accum per thread.
// ---------------------------------------------------------------------------
__global__ __launch_bounds__(256)
void qkv_proj(const float* __restrict__ x, const float* __restrict__ Wq,
              const float* __restrict__ Wk, const float* __restrict__ Wv,
              float* __restrict__ qo, float* __restrict__ ko, float* __restrict__ vo)
{
    const int which = blockIdx.z;
    const float* W = (which == 0) ? Wq : (which == 1) ? Wk : Wv;
    float* out = (which == 0) ? qo : (which == 1) ? ko : vo;
    const float scale = (which == 0) ? QSCALE : 1.0f;

    const int row0 = blockIdx.y * 64;
    const int col0 = blockIdx.x * 64;
    const int t = threadIdx.x;
    const int ty = t >> 4, tx = t & 15;

    __shared__ float As[16][68];   // k-major (transposed) A tile, pad for banks+align
    __shared__ float Bs[16][68];

    float acc[4][4] = {};

    const int lrow = t >> 2;        // 0..63 : A load row
    const int lk4  = (t & 3) * 4;   // 0,4,8,12 : A load k-offset
    const int bk   = t >> 4;        // 0..15 : B load k-row
    const int bc4  = (t & 15) * 4;  // 0..60 : B load col

    for (int kt = 0; kt < NF; kt += 16) {
        float4 a4 = *(const float4*)(x + (size_t)(row0 + lrow) * NF + kt + lk4);
        float4 b4 = *(const float4*)(W + (size_t)(kt + bk) * NF + col0 + bc4);
        __syncthreads();   // previous iteration's LDS reads done
        As[lk4 + 0][lrow] = a4.x;
        As[lk4 + 1][lrow] = a4.y;
        As[lk4 + 2][lrow] = a4.z;
        As[lk4 + 3][lrow] = a4.w;
        *(float4*)&Bs[bk][bc4] = b4;
        __syncthreads();
        #pragma unroll
        for (int kk = 0; kk < 16; ++kk) {
            float4 av = *(const float4*)&As[kk][ty * 4];
            float4 bv = *(const float4*)&Bs[kk][tx * 4];
            const float aa[4] = {av.x, av.y, av.z, av.w};
            const float bb[4] = {bv.x, bv.y, bv.z, bv.w};
            #pragma unroll
            for (int i = 0; i < 4; ++i)
                #pragma unroll
                for (int j = 0; j < 4; ++j)
                    acc[i][j] += aa[i] * bb[j];
        }
    }

    const int col = col0 + tx * 4;
    const int h = col >> 5;
    const int d = col & 31;
    #pragma unroll
    for (int i = 0; i < 4; ++i) {
        int row = row0 + ty * 4 + i;
        int b = row >> 11;        // row / 2048
        int s = row & 2047;
        float4 o;
        o.x = acc[i][0] * scale; o.y = acc[i][1] * scale;
        o.z = acc[i][2] * scale; o.w = acc[i][3] * scale;
        *(float4*)(out + ((size_t)(b * NH + h) * NS + s) * ND + d) = o;
    }
}

// ---------------------------------------------------------------------------
// Kernel 2: flash attention (fp32).  One block = 64 query rows of one (b,h).
// 256 threads: thread (qr = t>>2, g = t&3). q row lives in 32 VGPRs.
// Thread owns keys j === g (mod 4) for scores, and d-range [g*8, g*8+8) for PV.
// P is exchanged through LDS (within-wave producer/consumer, barrier for safety).
// ---------------------------------------------------------------------------
__global__ __launch_bounds__(256)
void attn(const float* __restrict__ q, const float* __restrict__ k,
          const float* __restrict__ v, float* __restrict__ ctx)
{
    const int bh = blockIdx.y;       // b*H + h
    const int s0 = blockIdx.x * 64;
    const int t = threadIdx.x;
    const int qr = t >> 2;           // 0..63
    const int g = t & 3;             // 0..3

    __shared__ float ks[64][36];
    __shared__ float vs[64][36];
    __shared__ float ps[64][65];

    float qreg[32];
    {
        const float* qrow = q + ((size_t)bh * NS + s0 + qr) * ND;
        #pragma unroll
        for (int i = 0; i < 8; ++i) {
            float4 t4 = *(const float4*)(qrow + i * 4);
            qreg[i*4+0]=t4.x; qreg[i*4+1]=t4.y; qreg[i*4+2]=t4.z; qreg[i*4+3]=t4.w;
        }
    }

    float m = -INFINITY, l = 0.0f;
    float acc[8] = {};

    const float* kb = k + (size_t)bh * NS * ND;
    const float* vb = v + (size_t)bh * NS * ND;

    for (int kt = 0; kt < NS; kt += 64) {
        __syncthreads();             // previous tile's PV reads complete
        #pragma unroll
        for (int rep = 0; rep < 2; ++rep) {
            int idx = t + rep * 256;
            int row = idx >> 3;
            int col = (idx & 7) * 4;
            *(float4*)&ks[row][col] = *(const float4*)(kb + (size_t)(kt + row) * ND + col);
            *(float4*)&vs[row][col] = *(const float4*)(vb + (size_t)(kt + row) * ND + col);
        }
        __syncthreads();

        float sc[16];
        float tmax = -INFINITY;
        #pragma unroll
        for (int jj = 0; jj < 16; ++jj) {
            int key = jj * 4 + g;
            float a0 = 0.f, a1 = 0.f, a2 = 0.f, a3 = 0.f;
            #pragma unroll
            for (int d4 = 0; d4 < 8; ++d4) {
                float4 k4 = *(const float4*)&ks[key][d4 * 4];
                a0 += qreg[d4*4+0] * k4.x;
                a1 += qreg[d4*4+1] * k4.y;
                a2 += qreg[d4*4+2] * k4.z;
                a3 += qreg[d4*4+3] * k4.w;
            }
            sc[jj] = (a0 + a1) + (a2 + a3);
            tmax = fmaxf(tmax, sc[jj]);
        }
        // row max across the 4 lanes sharing this q row
        tmax = fmaxf(tmax, __shfl_xor(tmax, 1));
        tmax = fmaxf(tmax, __shfl_xor(tmax, 2));
        float mnew = fmaxf(m, tmax);
        float corr = __expf(m - mnew);   // first tile: exp(-inf)=0
        float lsum = 0.0f;
        #pragma unroll
        for (int jj = 0; jj < 16; ++jj) {
            float p = __expf(sc[jj] - mnew);
            ps[qr][jj * 4 + g] = p;
            lsum += p;
        }
        lsum += __shfl_xor(lsum, 1);
        lsum += __shfl_xor(lsum, 2);
        l = l * corr + lsum;
        m = mnew;
        #pragma unroll
        for (int d = 0; d < 8; ++d) acc[d] *= corr;
        __syncthreads();             // all p values visible
        #pragma unroll 4
        for (int j = 0; j < 64; ++j) {
            float p = ps[qr][j];
            float4 v0 = *(const float4*)&vs[j][g * 8];
            float4 v1 = *(const float4*)&vs[j][g * 8 + 4];
            acc[0] += p * v0.x; acc[1] += p * v0.y;
            acc[2] += p * v0.z; acc[3] += p * v0.w;
            acc[4] += p * v1.x; acc[5] += p * v1.y;
            acc[6] += p * v1.z; acc[7] += p * v1.w;
        }
    }

    float inv = 1.0f / l;
    const int b = bh >> 3, h = bh & 7;
    float* op = ctx + ((size_t)b * NS + s0 + qr) * NF + h * ND + g * 8;
    float4 o0 = {acc[0]*inv, acc[1]*inv, acc[2]*inv, acc[3]*inv};
    float4 o1 = {acc[4]*inv, acc[5]*inv, acc[6]*inv, acc[7]*inv};
    *(float4*)(op) = o0;
    *(float4*)(op + 4) = o1;
}

// ---------------------------------------------------------------------------
// Kernel 3: y = relu(ctx @ Wf + bf); z = x + y; out = LayerNorm(z) per row.
// Block = 32 rows x full 256 cols.  Wave w owns rows w*8..w*8+7 exclusively,
// so LN reductions are pure wave shuffles.
// ---------------------------------------------------------------------------
__global__ __launch_bounds__(256)
void dense_ln(const float* __restrict__ ctx, const float* __restrict__ Wf,
              const float* __restrict__ bfp, const float* __restrict__ x,
              float* __restrict__ out)
{
    const int r0 = blockIdx.x * 32;
    const int t = threadIdx.x;
    const int w = t >> 6;        // wave 0..3
    const int lane = t & 63;
    const int c0 = lane * 4;     // this thread's 4 columns

    __shared__ float As[32][36];
    __shared__ float Bs[32][260];

    float acc[8][4] = {};

    const int arow = t >> 3;          // 0..31
    const int ak4  = (t & 7) * 4;     // 0..28

    for (int kt = 0; kt < NF; kt += 32) {
        __syncthreads();
        *(float4*)&As[arow][ak4] = *(const float4*)(ctx + (size_t)(r0 + arow) * NF + kt + ak4);
        #pragma unroll
        for (int rep = 0; rep < 8; ++rep) {
            int idx = t + rep * 256;
            int row = idx >> 6;          // 0..31
            int col = (idx & 63) * 4;
            *(float4*)&Bs[row][col] = *(const float4*)(Wf + (size_t)(kt + row) * NF + col);
        }
        __syncthreads();
        #pragma unroll
        for (int kk = 0; kk < 32; ++kk) {
            float4 bv = *(const float4*)&Bs[kk][c0];
            const float bb[4] = {bv.x, bv.y, bv.z, bv.w};
            #pragma unroll
            for (int i = 0; i < 8; ++i) {
                float a = As[w * 8 + i][kk];   // wave-uniform broadcast
                acc[i][0] += a * bb[0];
                acc[i][1] += a * bb[1];
                acc[i][2] += a * bb[2];
                acc[i][3] += a * bb[3];
            }
        }
    }

    float4 bias = *(const float4*)(bfp + c0);
    #pragma unroll
    for (int i = 0; i < 8; ++i) {
        int row = r0 + w * 8 + i;
        float4 xv = *(const float4*)(x + (size_t)row * NF + c0);
        float z0 = xv.x + fmaxf(acc[i][0] + bias.x, 0.0f);
        float z1 = xv.y + fmaxf(acc[i][1] + bias.y, 0.0f);
        float z2 = xv.z + fmaxf(acc[i][2] + bias.z, 0.0f);
        float z3 = xv.w + fmaxf(acc[i][3] + bias.w, 0.0f);
        float sum = z0 + z1 + z2 + z3;
        float sq  = z0*z0 + z1*z1 + z2*z2 + z3*z3;
        #pragma unroll
        for (int o = 1; o < 64; o <<= 1) {
            sum += __shfl_xor(sum, o);
            sq  += __shfl_xor(sq, o);
        }
        float mean = sum * (1.0f / NF);
        float var  = sq * (1.0f / NF) - mean * mean;
        float rstd = rsqrtf(var + LN_EPS);
        float4 o4;
        o4.x = (z0 - mean) * rstd;
        o4.y = (z1 - mean) * rstd;
        o4.z = (z2 - mean) * rstd;
        o4.w = (z3 - mean) * rstd;
        *(float4*)(out + (size_t)row * NF + c0) = o4;
    }
}

// ---------------------------------------------------------------------------
extern "C" void kernel_launch(void* const* d_in, const int* in_sizes, int n_in,
                              void* d_out, int out_size, void* d_ws, size_t ws_size,
                              hipStream_t stream)
{
    const float* x  = (const float*)d_in[0];
    const float* Wq = (const float*)d_in[1];
    const float* Wk = (const float*)d_in[2];
    const float* Wv = (const float*)d_in[3];
    const float* Wf = (const float*)d_in[4];
    const float* bf = (const float*)d_in[5];
    float* out = (float*)d_out;

    float* ws = (float*)d_ws;
    const size_t per = (size_t)NB * NH * NS * ND;   // 2M floats
    float* q   = ws;
    float* k   = q + per;
    float* v   = k + per;
    float* ctx = v + per;                           // B*S*F floats

    qkv_proj<<<dim3(4, 128, 3), 256, 0, stream>>>(x, Wq, Wk, Wv, q, k, v);
    attn<<<dim3(NS / 64, NB * NH), 256, 0, stream>>>(q, k, v, ctx);
    dense_ln<<<dim3((NB * NS) / 32), 256, 0, stream>>>(ctx, Wf, bf, x, out);
}

// Round 2
// 169.806 us; speedup vs baseline: 2.6009x; 2.6009x over previous
//
#include <hip/hip_runtime.h>
#include <math.h>

#define NB 4
#define NS 2048
#define NF 256
#define NH 8
#define ND 32

constexpr float LN_EPS = 1e-3f;
constexpr float QSCALE = 0.35355339059327373f; // 1/sqrt(H)

typedef __bf16 bf16x8 __attribute__((ext_vector_type(8)));
typedef float f32x4 __attribute__((ext_vector_type(4)));

__device__ __forceinline__ unsigned short f2b(float x) {
    union { float f; unsigned u; } c; c.f = x;
    unsigned r = (c.u + 0x7FFFu + ((c.u >> 16) & 1u)) >> 16;  // RNE
    return (unsigned short)r;
}

// ---------------------------------------------------------------------------
// Kernel 1: QKV projection (fp32 GEMM, bf16 output in [B,H,S,D] layout).
// ---------------------------------------------------------------------------
__global__ __launch_bounds__(256)
void qkv_proj(const float* __restrict__ x, const float* __restrict__ Wq,
              const float* __restrict__ Wk, const float* __restrict__ Wv,
              unsigned short* __restrict__ qo, unsigned short* __restrict__ ko,
              unsigned short* __restrict__ vo)
{
    const int which = blockIdx.z;
    const float* W = (which == 0) ? Wq : (which == 1) ? Wk : Wv;
    unsigned short* out = (which == 0) ? qo : (which == 1) ? ko : vo;
    const float scale = (which == 0) ? QSCALE : 1.0f;

    const int row0 = blockIdx.y * 64;
    const int col0 = blockIdx.x * 64;
    const int t = threadIdx.x;
    const int ty = t >> 4, tx = t & 15;

    __shared__ float As[16][68];
    __shared__ float Bs[16][68];

    float acc[4][4] = {};

    const int lrow = t >> 2;
    const int lk4  = (t & 3) * 4;
    const int bk   = t >> 4;
    const int bc4  = (t & 15) * 4;

    for (int kt = 0; kt < NF; kt += 16) {
        float4 a4 = *(const float4*)(x + (size_t)(row0 + lrow) * NF + kt + lk4);
        float4 b4 = *(const float4*)(W + (size_t)(kt + bk) * NF + col0 + bc4);
        __syncthreads();
        As[lk4 + 0][lrow] = a4.x;
        As[lk4 + 1][lrow] = a4.y;
        As[lk4 + 2][lrow] = a4.z;
        As[lk4 + 3][lrow] = a4.w;
        *(float4*)&Bs[bk][bc4] = b4;
        __syncthreads();
        #pragma unroll
        for (int kk = 0; kk < 16; ++kk) {
            float4 av = *(const float4*)&As[kk][ty * 4];
            float4 bv = *(const float4*)&Bs[kk][tx * 4];
            const float aa[4] = {av.x, av.y, av.z, av.w};
            const float bb[4] = {bv.x, bv.y, bv.z, bv.w};
            #pragma unroll
            for (int i = 0; i < 4; ++i)
                #pragma unroll
                for (int j = 0; j < 4; ++j)
                    acc[i][j] += aa[i] * bb[j];
        }
    }

    const int col = col0 + tx * 4;
    const int h = col >> 5;
    const int d = col & 31;
    #pragma unroll
    for (int i = 0; i < 4; ++i) {
        int row = row0 + ty * 4 + i;
        int b = row >> 11;
        int s = row & 2047;
        ushort4 o;
        o.x = f2b(acc[i][0] * scale);
        o.y = f2b(acc[i][1] * scale);
        o.z = f2b(acc[i][2] * scale);
        o.w = f2b(acc[i][3] * scale);
        *(ushort4*)(out + ((size_t)(b * NH + h) * NS + s) * ND + d) = o;
    }
}

// ---------------------------------------------------------------------------
// Kernel 2: flash attention with bf16 MFMA (f32 accum).
// Block = 4 waves x 16 q-rows = 64 q-rows of one (b,h); KV tile = 64 keys.
// QK^T: A = Q (held in regs), B = K fragments loaded direct from global (L2).
// Softmax on C-layout (row=(l>>4)*4+r, col=l&15), 16-lane shuffle reductions.
// PV: P staged bf16 in LDS [q][key] (stride 72), V staged transposed [d][key].
// ---------------------------------------------------------------------------
__global__ __launch_bounds__(256)
void attn_mfma(const unsigned short* __restrict__ q, const unsigned short* __restrict__ k,
               const unsigned short* __restrict__ v, float* __restrict__ ctx)
{
    const int bh = blockIdx.y;
    const int s0 = blockIdx.x * 64;
    const int t = threadIdx.x;
    const int w = t >> 6;
    const int lane = t & 63;
    const int l15 = lane & 15;
    const int lhi = lane >> 4;   // 0..3

    __shared__ unsigned short ps[64][72];  // P: [q within block][key within tile]
    __shared__ unsigned short vt[32][72];  // V^T: [d][key within tile]

    const unsigned short* qb = q + (size_t)bh * NS * ND;
    const unsigned short* kb = k + (size_t)bh * NS * ND;
    const unsigned short* vb = v + (size_t)bh * NS * ND;

    // A-fragment: lane holds Q[row=l15][k=lhi*8 + i], rows are this wave's 16 q-rows
    bf16x8 qfrag = *(const bf16x8*)(qb + (size_t)(s0 + w * 16 + l15) * ND + lhi * 8);

    float mr[4] = {-INFINITY, -INFINITY, -INFINITY, -INFINITY};
    float lr[4] = {0.f, 0.f, 0.f, 0.f};
    f32x4 acc0 = {0.f, 0.f, 0.f, 0.f};
    f32x4 acc1 = {0.f, 0.f, 0.f, 0.f};

    for (int kt = 0; kt < NS; kt += 64) {
        __syncthreads();   // previous tile's PV reads of vt complete
        // stage V transposed: wave w owns d rows [w*8, w*8+8), lane = key index
        {
            bf16x8 vv = *(const bf16x8*)(vb + (size_t)(kt + lane) * ND + w * 8);
            union { bf16x8 v8; unsigned short s[8]; } u; u.v8 = vv;
            #pragma unroll
            for (int i = 0; i < 8; ++i) vt[w * 8 + i][lane] = u.s[i];
        }

        // QK^T: 4 fragments of 16 keys, K direct from global (L2-resident)
        const f32x4 zero = {0.f, 0.f, 0.f, 0.f};
        f32x4 sc[4];
        #pragma unroll
        for (int f = 0; f < 4; ++f) {
            bf16x8 kf = *(const bf16x8*)(kb + (size_t)(kt + f * 16 + l15) * ND + lhi * 8);
            sc[f] = __builtin_amdgcn_mfma_f32_16x16x32_bf16(qfrag, kf, zero, 0, 0, 0);
        }

        // online softmax; q-row r lives in the 16-lane group, register r
        float corr[4];
        #pragma unroll
        for (int r = 0; r < 4; ++r) {
            float tm = fmaxf(fmaxf(sc[0][r], sc[1][r]), fmaxf(sc[2][r], sc[3][r]));
            tm = fmaxf(tm, __shfl_xor(tm, 1));
            tm = fmaxf(tm, __shfl_xor(tm, 2));
            tm = fmaxf(tm, __shfl_xor(tm, 4));
            tm = fmaxf(tm, __shfl_xor(tm, 8));
            float mn = fmaxf(mr[r], tm);
            corr[r] = __expf(mr[r] - mn);
            mr[r] = mn;
            float ls = 0.f;
            #pragma unroll
            for (int f = 0; f < 4; ++f) {
                float p = __expf(sc[f][r] - mn);
                ps[w * 16 + lhi * 4 + r][f * 16 + l15] = f2b(p);
                ls += p;
            }
            ls += __shfl_xor(ls, 1);
            ls += __shfl_xor(ls, 2);
            ls += __shfl_xor(ls, 4);
            ls += __shfl_xor(ls, 8);
            lr[r] = lr[r] * corr[r] + ls;
        }
        #pragma unroll
        for (int r = 0; r < 4; ++r) { acc0[r] *= corr[r]; acc1[r] *= corr[r]; }

        __syncthreads();   // vt writes (all waves) visible

        // PV: ctx[16q x 32d] += P[16q x 64key] * V[64key x 32d]
        #pragma unroll
        for (int c = 0; c < 2; ++c) {
            bf16x8 pa  = *(const bf16x8*)&ps[w * 16 + l15][c * 32 + lhi * 8];
            bf16x8 vf0 = *(const bf16x8*)&vt[l15][c * 32 + lhi * 8];
            bf16x8 vf1 = *(const bf16x8*)&vt[16 + l15][c * 32 + lhi * 8];
            acc0 = __builtin_amdgcn_mfma_f32_16x16x32_bf16(pa, vf0, acc0, 0, 0, 0);
            acc1 = __builtin_amdgcn_mfma_f32_16x16x32_bf16(pa, vf1, acc1, 0, 0, 0);
        }
    }

    const int b = bh >> 3, h = bh & 7;
    #pragma unroll
    for (int r = 0; r < 4; ++r) {
        float inv = 1.0f / lr[r];
        int row = s0 + w * 16 + lhi * 4 + r;
        float* op = ctx + ((size_t)b * NS + row) * NF + h * ND;
        op[l15]      = acc0[r] * inv;
        op[16 + l15] = acc1[r] * inv;
    }
}

// ---------------------------------------------------------------------------
// Kernel 3: y = relu(ctx @ Wf + bf); z = x + y; out = LayerNorm(z).
// ---------------------------------------------------------------------------
__global__ __launch_bounds__(256)
void dense_ln(const float* __restrict__ ctx, const float* __restrict__ Wf,
              const float* __restrict__ bfp, const float* __restrict__ x,
              float* __restrict__ out)
{
    const int r0 = blockIdx.x * 32;
    const int t = threadIdx.x;
    const int w = t >> 6;
    const int lane = t & 63;
    const int c0 = lane * 4;

    __shared__ float As[32][36];
    __shared__ float Bs[32][260];

    float acc[8][4] = {};

    const int arow = t >> 3;
    const int ak4  = (t & 7) * 4;

    for (int kt = 0; kt < NF; kt += 32) {
        __syncthreads();
        *(float4*)&As[arow][ak4] = *(const float4*)(ctx + (size_t)(r0 + arow) * NF + kt + ak4);
        #pragma unroll
        for (int rep = 0; rep < 8; ++rep) {
            int idx = t + rep * 256;
            int row = idx >> 6;
            int col = (idx & 63) * 4;
            *(float4*)&Bs[row][col] = *(const float4*)(Wf + (size_t)(kt + row) * NF + col);
        }
        __syncthreads();
        #pragma unroll
        for (int kk = 0; kk < 32; ++kk) {
            float4 bv = *(const float4*)&Bs[kk][c0];
            const float bb[4] = {bv.x, bv.y, bv.z, bv.w};
            #pragma unroll
            for (int i = 0; i < 8; ++i) {
                float a = As[w * 8 + i][kk];
                acc[i][0] += a * bb[0];
                acc[i][1] += a * bb[1];
                acc[i][2] += a * bb[2];
                acc[i][3] += a * bb[3];
            }
        }
    }

    float4 bias = *(const float4*)(bfp + c0);
    #pragma unroll
    for (int i = 0; i < 8; ++i) {
        int row = r0 + w * 8 + i;
        float4 xv = *(const float4*)(x + (size_t)row * NF + c0);
        float z0 = xv.x + fmaxf(acc[i][0] + bias.x, 0.0f);
        float z1 = xv.y + fmaxf(acc[i][1] + bias.y, 0.0f);
        float z2 = xv.z + fmaxf(acc[i][2] + bias.z, 0.0f);
        float z3 = xv.w + fmaxf(acc[i][3] + bias.w, 0.0f);
        float sum = z0 + z1 + z2 + z3;
        float sq  = z0*z0 + z1*z1 + z2*z2 + z3*z3;
        #pragma unroll
        for (int o = 1; o < 64; o <<= 1) {
            sum += __shfl_xor(sum, o);
            sq  += __shfl_xor(sq, o);
        }
        float mean = sum * (1.0f / NF);
        float var  = sq * (1.0f / NF) - mean * mean;
        float rstd = rsqrtf(var + LN_EPS);
        float4 o4;
        o4.x = (z0 - mean) * rstd;
        o4.y = (z1 - mean) * rstd;
        o4.z = (z2 - mean) * rstd;
        o4.w = (z3 - mean) * rstd;
        *(float4*)(out + (size_t)row * NF + c0) = o4;
    }
}

// ---------------------------------------------------------------------------
extern "C" void kernel_launch(void* const* d_in, const int* in_sizes, int n_in,
                              void* d_out, int out_size, void* d_ws, size_t ws_size,
                              hipStream_t stream)
{
    const float* x  = (const float*)d_in[0];
    const float* Wq = (const float*)d_in[1];
    const float* Wk = (const float*)d_in[2];
    const float* Wv = (const float*)d_in[3];
    const float* Wf = (const float*)d_in[4];
    const float* bf = (const float*)d_in[5];
    float* out = (float*)d_out;

    const size_t per = (size_t)NB * NH * NS * ND;   // 2M elements
    unsigned short* q  = (unsigned short*)d_ws;
    unsigned short* kk = q + per;
    unsigned short* vv = kk + per;
    float* ctx = (float*)(vv + per);                // fp32, B*S*F

    qkv_proj<<<dim3(4, 128, 3), 256, 0, stream>>>(x, Wq, Wk, Wv, q, kk, vv);
    attn_mfma<<<dim3(NS / 64, NB * NH), 256, 0, stream>>>(q, kk, vv, ctx);
    dense_ln<<<dim3((NB * NS) / 32), 256, 0, stream>>>(ctx, Wf, bf, x, out);
}

// Round 3
// 112.460 us; speedup vs baseline: 3.9272x; 1.5099x over previous
//
#include <hip/hip_runtime.h>
#include <math.h>

#define NB 4
#define NS 2048
#define NF 256
#define NH 8
#define ND 32

constexpr float LN_EPS = 1e-3f;
constexpr float QSCALE = 0.35355339059327373f; // 1/sqrt(H)

typedef __bf16 bf16x8 __attribute__((ext_vector_type(8)));
typedef float f32x4 __attribute__((ext_vector_type(4)));

// ---------------------------------------------------------------------------
// Pre-pass A: x fp32 -> bf16
// ---------------------------------------------------------------------------
__global__ __launch_bounds__(256)
void cvt_x(const float* __restrict__ x, unsigned short* __restrict__ xb)
{
    const int i = (blockIdx.x * 256 + threadIdx.x) * 8;
    float4 a = *(const float4*)(x + i);
    float4 b = *(const float4*)(x + i + 4);
    union { ushort4 u; __bf16 h[4]; } o0, o1;
    o0.h[0] = (__bf16)a.x; o0.h[1] = (__bf16)a.y; o0.h[2] = (__bf16)a.z; o0.h[3] = (__bf16)a.w;
    o1.h[0] = (__bf16)b.x; o1.h[1] = (__bf16)b.y; o1.h[2] = (__bf16)b.z; o1.h[3] = (__bf16)b.w;
    *(ushort4*)(xb + i) = o0.u;
    *(ushort4*)(xb + i + 4) = o1.u;
}

// ---------------------------------------------------------------------------
// Pre-pass B: W[k][n] fp32 -> Wt[n][k] bf16 (QSCALE folded into Wq).
// ---------------------------------------------------------------------------
__global__ __launch_bounds__(256)
void prep_w(const float* __restrict__ Wq, const float* __restrict__ Wk,
            const float* __restrict__ Wv, unsigned short* __restrict__ wt)
{
    const int z = blockIdx.z;
    const float* W = (z == 0) ? Wq : (z == 1) ? Wk : Wv;
    const float scale = (z == 0) ? QSCALE : 1.0f;
    const int r0 = blockIdx.y * 64, c0 = blockIdx.x * 64;
    const int t = threadIdx.x;
    const int tr = t >> 4, tc4 = (t & 15) * 4;

    __shared__ float tile[64][65];
    #pragma unroll
    for (int p = 0; p < 4; ++p) {
        float4 v = *(const float4*)(W + (size_t)(r0 + tr + p * 16) * NF + c0 + tc4);
        tile[tr + p * 16][tc4 + 0] = v.x;
        tile[tr + p * 16][tc4 + 1] = v.y;
        tile[tr + p * 16][tc4 + 2] = v.z;
        tile[tr + p * 16][tc4 + 3] = v.w;
    }
    __syncthreads();
    #pragma unroll
    for (int p = 0; p < 4; ++p) {
        union { ushort4 u; __bf16 h[4]; } o;
        #pragma unroll
        for (int j = 0; j < 4; ++j)
            o.h[j] = (__bf16)(tile[tc4 + j][tr + p * 16] * scale);
        *(ushort4*)(wt + (size_t)z * 65536 + (size_t)(c0 + tr + p * 16) * NF + r0 + tc4) = o.u;
    }
}

// ---------------------------------------------------------------------------
// Kernel 1: QKV projection, bf16 MFMA.  Block = 64 rows x 256 cols, 4 waves
// (wr,wc) in 2x2; wave = 32 rows x 128 cols = 2 A-frags x 8 B-frags.
// ---------------------------------------------------------------------------
__global__ __launch_bounds__(256)
void qkv_mfma(const unsigned short* __restrict__ xb, const unsigned short* __restrict__ wt,
              unsigned short* __restrict__ qo, unsigned short* __restrict__ ko,
              unsigned short* __restrict__ vo)
{
    const int z = blockIdx.y;
    unsigned short* out = (z == 0) ? qo : (z == 1) ? ko : vo;
    const unsigned short* W = wt + (size_t)z * 65536;   // Wt[n][k] bf16

    const int r0 = blockIdx.x * 64;
    const int t = threadIdx.x;
    const int w = t >> 6, lane = t & 63;
    const int l15 = lane & 15, lhi = lane >> 4;
    const int wr = w >> 1, wc = w & 1;

    f32x4 acc[2][8] = {};

    for (int kt = 0; kt < NF; kt += 32) {
        bf16x8 a0 = *(const bf16x8*)(xb + (size_t)(r0 + wr * 32 + l15) * NF + kt + lhi * 8);
        bf16x8 a1 = *(const bf16x8*)(xb + (size_t)(r0 + wr * 32 + 16 + l15) * NF + kt + lhi * 8);
        #pragma unroll
        for (int c = 0; c < 8; ++c) {
            bf16x8 b = *(const bf16x8*)(W + (size_t)(wc * 128 + c * 16 + l15) * NF + kt + lhi * 8);
            acc[0][c] = __builtin_amdgcn_mfma_f32_16x16x32_bf16(a0, b, acc[0][c], 0, 0, 0);
            acc[1][c] = __builtin_amdgcn_mfma_f32_16x16x32_bf16(a1, b, acc[1][c], 0, 0, 0);
        }
    }

    #pragma unroll
    for (int i = 0; i < 2; ++i) {
        #pragma unroll
        for (int c = 0; c < 8; ++c) {
            const int col = wc * 128 + c * 16 + l15;
            const int h = col >> 5, d = col & 31;
            #pragma unroll
            for (int r = 0; r < 4; ++r) {
                const int row = r0 + wr * 32 + i * 16 + lhi * 4 + r;
                const int b = row >> 11, s = row & 2047;
                __bf16 o = (__bf16)acc[i][c][r];
                out[((size_t)(b * NH + h) * NS + s) * ND + d] = *(unsigned short*)&o;
            }
        }
    }
}

// ---------------------------------------------------------------------------
// Kernel 2: flash attention, swapped QK^T (mfma(K,Q)) for in-register softmax.
// Block = 4 waves x 16 q-rows; grid (bh, s-tile) for XCD L2 locality.
// One barrier per tile (V double-buffered); P per-wave in LDS (no barrier).
// K prefetched one tile ahead into registers.
// ---------------------------------------------------------------------------
__global__ __launch_bounds__(256)
void attn_mfma(const unsigned short* __restrict__ q, const unsigned short* __restrict__ k,
               const unsigned short* __restrict__ v, float* __restrict__ ctx)
{
    const int bh = blockIdx.x;            // XCD = bh % 8 (heuristic swizzle)
    const int s0 = blockIdx.y * 64;
    const int t = threadIdx.x;
    const int w = t >> 6;
    const int lane = t & 63;
    const int l15 = lane & 15;
    const int lhi = lane >> 4;

    __shared__ unsigned short ps[4][16][72];   // per-wave P [q=l15][key]
    __shared__ unsigned short vt[2][32][72];   // V^T dbuf [d][key]

    const unsigned short* qb = q + (size_t)bh * NS * ND;
    const unsigned short* kb = k + (size_t)bh * NS * ND;
    const unsigned short* vb = v + (size_t)bh * NS * ND;

    // Q B-operand fragment: lane holds Q[q=l15][d=lhi*8..+7] (wave's 16 q-rows)
    bf16x8 qfrag = *(const bf16x8*)(qb + (size_t)(s0 + w * 16 + l15) * ND + lhi * 8);

    float m_col = -INFINITY, l_col = 0.0f;     // stats for q = l15
    f32x4 acc0 = {0.f, 0.f, 0.f, 0.f};        // ctx rows q = lhi*4+r, d = l15
    f32x4 acc1 = {0.f, 0.f, 0.f, 0.f};        // d = 16 + l15

    // ---- prologue: tile 0 ----
    bf16x8 kf[4], kn[4];
    #pragma unroll
    for (int f = 0; f < 4; ++f)
        kf[f] = *(const bf16x8*)(kb + (size_t)(f * 16 + l15) * ND + lhi * 8);
    {
        bf16x8 vv = *(const bf16x8*)(vb + (size_t)lane * ND + w * 8);
        union { bf16x8 v8; unsigned short s[8]; } u; u.v8 = vv;
        #pragma unroll
        for (int i = 0; i < 8; ++i) vt[0][w * 8 + i][lane] = u.s[i];
    }
    __syncthreads();

    int cur = 0;
    for (int tI = 0; tI < 32; ++tI) {
        const int ktn = ((tI + 1) & 31) * 64;   // wraps on last iter (harmless)
        // prefetch next tile: V rows -> regs, K fragments -> regs
        bf16x8 vv = *(const bf16x8*)(vb + (size_t)(ktn + lane) * ND + w * 8);
        #pragma unroll
        for (int f = 0; f < 4; ++f)
            kn[f] = *(const bf16x8*)(kb + (size_t)(ktn + f * 16 + l15) * ND + lhi * 8);

        // QK^T swapped: sc[f][r] = S[key = f*16+lhi*4+r][q = l15]
        const f32x4 zero = {0.f, 0.f, 0.f, 0.f};
        f32x4 sc[4];
        __builtin_amdgcn_s_setprio(1);
        #pragma unroll
        for (int f = 0; f < 4; ++f)
            sc[f] = __builtin_amdgcn_mfma_f32_16x16x32_bf16(kf[f], qfrag, zero, 0, 0, 0);
        __builtin_amdgcn_s_setprio(0);

        // ---- online softmax for q = l15 (in-register over 16 keys) ----
        float tmax = sc[0][0];
        #pragma unroll
        for (int f = 0; f < 4; ++f)
            #pragma unroll
            for (int r = 0; r < 4; ++r)
                tmax = fmaxf(tmax, sc[f][r]);
        tmax = fmaxf(tmax, __shfl_xor(tmax, 16));
        tmax = fmaxf(tmax, __shfl_xor(tmax, 32));
        const float mnew = fmaxf(m_col, tmax);
        const float corr_col = __expf(m_col - mnew);
        m_col = mnew;

        float ls = 0.0f;
        #pragma unroll
        for (int f = 0; f < 4; ++f) {
            float p0 = __expf(sc[f][0] - mnew);
            float p1 = __expf(sc[f][1] - mnew);
            float p2 = __expf(sc[f][2] - mnew);
            float p3 = __expf(sc[f][3] - mnew);
            ls += (p0 + p1) + (p2 + p3);
            union { ushort4 u; __bf16 h[4]; } pk;
            pk.h[0] = (__bf16)p0; pk.h[1] = (__bf16)p1;
            pk.h[2] = (__bf16)p2; pk.h[3] = (__bf16)p3;
            *(ushort4*)&ps[w][l15][f * 16 + lhi * 4] = pk.u;
        }
        ls += __shfl_xor(ls, 16);
        ls += __shfl_xor(ls, 32);
        l_col = l_col * corr_col + ls;

        // move corr to acc layout (q = lhi*4+r) and rescale
        #pragma unroll
        for (int r = 0; r < 4; ++r) {
            float cr = __shfl(corr_col, lhi * 4 + r);
            acc0[r] *= cr;
            acc1[r] *= cr;
        }

        // PV: acc[16q x 32d] += P[16q x 64k] * V[64k x 32d]
        __builtin_amdgcn_s_setprio(1);
        #pragma unroll
        for (int c = 0; c < 2; ++c) {
            bf16x8 pa  = *(const bf16x8*)&ps[w][l15][c * 32 + lhi * 8];
            bf16x8 vf0 = *(const bf16x8*)&vt[cur][l15][c * 32 + lhi * 8];
            bf16x8 vf1 = *(const bf16x8*)&vt[cur][16 + l15][c * 32 + lhi * 8];
            acc0 = __builtin_amdgcn_mfma_f32_16x16x32_bf16(pa, vf0, acc0, 0, 0, 0);
            acc1 = __builtin_amdgcn_mfma_f32_16x16x32_bf16(pa, vf1, acc1, 0, 0, 0);
        }
        __builtin_amdgcn_s_setprio(0);

        // stage prefetched V into the other buffer, rotate K regs
        {
            union { bf16x8 v8; unsigned short s[8]; } u; u.v8 = vv;
            #pragma unroll
            for (int i = 0; i < 8; ++i) vt[cur ^ 1][w * 8 + i][lane] = u.s[i];
        }
        #pragma unroll
        for (int f = 0; f < 4; ++f) kf[f] = kn[f];
        __syncthreads();
        cur ^= 1;
    }

    const int b = bh >> 3, h = bh & 7;
    #pragma unroll
    for (int r = 0; r < 4; ++r) {
        float li = __shfl(l_col, lhi * 4 + r);
        float inv = 1.0f / li;
        int row = s0 + w * 16 + lhi * 4 + r;
        float* op = ctx + ((size_t)b * NS + row) * NF + h * ND;
        op[l15]      = acc0[r] * inv;
        op[16 + l15] = acc1[r] * inv;
    }
}

// ---------------------------------------------------------------------------
// Kernel 3: y = relu(ctx @ Wf + bf); z = x + y; out = LayerNorm(z).
// ---------------------------------------------------------------------------
__global__ __launch_bounds__(256)
void dense_ln(const float* __restrict__ ctx, const float* __restrict__ Wf,
              const float* __restrict__ bfp, const float* __restrict__ x,
              float* __restrict__ out)
{
    const int r0 = blockIdx.x * 32;
    const int t = threadIdx.x;
    const int w = t >> 6;
    const int lane = t & 63;
    const int c0 = lane * 4;

    __shared__ float As[32][36];
    __shared__ float Bs[32][260];

    float acc[8][4] = {};

    const int arow = t >> 3;
    const int ak4  = (t & 7) * 4;

    for (int kt = 0; kt < NF; kt += 32) {
        __syncthreads();
        *(float4*)&As[arow][ak4] = *(const float4*)(ctx + (size_t)(r0 + arow) * NF + kt + ak4);
        #pragma unroll
        for (int rep = 0; rep < 8; ++rep) {
            int idx = t + rep * 256;
            int row = idx >> 6;
            int col = (idx & 63) * 4;
            *(float4*)&Bs[row][col] = *(const float4*)(Wf + (size_t)(kt + row) * NF + col);
        }
        __syncthreads();
        #pragma unroll
        for (int kk = 0; kk < 32; ++kk) {
            float4 bv = *(const float4*)&Bs[kk][c0];
            const float bb[4] = {bv.x, bv.y, bv.z, bv.w};
            #pragma unroll
            for (int i = 0; i < 8; ++i) {
                float a = As[w * 8 + i][kk];
                acc[i][0] += a * bb[0];
                acc[i][1] += a * bb[1];
                acc[i][2] += a * bb[2];
                acc[i][3] += a * bb[3];
            }
        }
    }

    float4 bias = *(const float4*)(bfp + c0);
    #pragma unroll
    for (int i = 0; i < 8; ++i) {
        int row = r0 + w * 8 + i;
        float4 xv = *(const float4*)(x + (size_t)row * NF + c0);
        float z0 = xv.x + fmaxf(acc[i][0] + bias.x, 0.0f);
        float z1 = xv.y + fmaxf(acc[i][1] + bias.y, 0.0f);
        float z2 = xv.z + fmaxf(acc[i][2] + bias.z, 0.0f);
        float z3 = xv.w + fmaxf(acc[i][3] + bias.w, 0.0f);
        float sum = z0 + z1 + z2 + z3;
        float sq  = z0*z0 + z1*z1 + z2*z2 + z3*z3;
        #pragma unroll
        for (int o = 1; o < 64; o <<= 1) {
            sum += __shfl_xor(sum, o);
            sq  += __shfl_xor(sq, o);
        }
        float mean = sum * (1.0f / NF);
        float var  = sq * (1.0f / NF) - mean * mean;
        float rstd = rsqrtf(var + LN_EPS);
        float4 o4;
        o4.x = (z0 - mean) * rstd;
        o4.y = (z1 - mean) * rstd;
        o4.z = (z2 - mean) * rstd;
        o4.w = (z3 - mean) * rstd;
        *(float4*)(out + (size_t)row * NF + c0) = o4;
    }
}

// ---------------------------------------------------------------------------
extern "C" void kernel_launch(void* const* d_in, const int* in_sizes, int n_in,
                              void* d_out, int out_size, void* d_ws, size_t ws_size,
                              hipStream_t stream)
{
    const float* x  = (const float*)d_in[0];
    const float* Wq = (const float*)d_in[1];
    const float* Wk = (const float*)d_in[2];
    const float* Wv = (const float*)d_in[3];
    const float* Wf = (const float*)d_in[4];
    const float* bf = (const float*)d_in[5];
    float* out = (float*)d_out;

    const size_t per = (size_t)NB * NH * NS * ND;   // 2M elements
    unsigned short* q  = (unsigned short*)d_ws;
    unsigned short* kk = q + per;
    unsigned short* vv = kk + per;
    unsigned short* xb = vv + per;
    unsigned short* wt = xb + per;                  // 3 * 64K bf16
    float* ctx = (float*)(wt + 3 * 65536);          // fp32, B*S*F

    cvt_x<<<dim3((int)(per / (8 * 256))), 256, 0, stream>>>(x, xb);
    prep_w<<<dim3(4, 4, 3), 256, 0, stream>>>(Wq, Wk, Wv, wt);
    qkv_mfma<<<dim3(128, 3), 256, 0, stream>>>(xb, wt, q, kk, vv);
    attn_mfma<<<dim3(NB * NH, NS / 64), 256, 0, stream>>>(q, kk, vv, ctx);
    dense_ln<<<dim3((NB * NS) / 32), 256, 0, stream>>>(ctx, Wf, bf, x, out);
}